// Round 1
// baseline (3225.373 us; speedup 1.0000x reference)
//
#include <hip/hip_runtime.h>
#include <math.h>

#define N_NODES 50000
#define N_EDGES 600000
#define HID 128
#define N_GRAPHS 64

__device__ __forceinline__ float softplus_f(float v) {
    // jax.nn.softplus = logaddexp(v, 0) = max(v,0) + log1p(exp(-|v|))
    return fmaxf(v, 0.0f) + log1pf(expf(-fabsf(v)));
}

// One wave per edge; lane l handles features [2l, 2l+1].
__global__ void edge_agg_kernel(const float* __restrict__ x,
                                const float* __restrict__ edge_attr,
                                const int* __restrict__ ei,
                                float* __restrict__ agg) {
    int wave = blockIdx.x * 4 + (threadIdx.x >> 6);
    int lane = threadIdx.x & 63;
    if (wave >= N_EDGES) return;
    int e = __builtin_amdgcn_readfirstlane(wave);
    int src = ei[e];            // scalar loads (uniform index)
    int dst = ei[N_EDGES + e];
    const float2* xr = (const float2*)(x + (size_t)src * HID);
    const float2* er = (const float2*)(edge_attr + (size_t)e * HID);
    float2 xv = xr[lane];
    float2 ev = er[lane];
    float m0 = softplus_f(xv.x + ev.x);
    float m1 = softplus_f(xv.y + ev.y);
    float* ap = agg + (size_t)dst * HID + lane * 2;
    unsafeAtomicAdd(ap, m0);
    unsafeAtomicAdd(ap + 1, m1);
}

// y[n,:] = act( A[n,:] @ W^T + b ), A = A1 (+ A2 if non-null).
// Wave w: lanes = 64 consecutive nodes, jbase = (w&3)*32 (uniform per wave)
// => W/B accesses are wave-uniform -> scalar loads, inner loop pure v_fma.
__global__ void __launch_bounds__(256) mlp_kernel(
        const float* __restrict__ A1,
        const float* __restrict__ A2,
        const float* __restrict__ W,
        const float* __restrict__ Bv,
        float* __restrict__ out,
        int apply_sp) {
    int w = blockIdx.x * 4 + (threadIdx.x >> 6);
    w = __builtin_amdgcn_readfirstlane(w);
    int lane = threadIdx.x & 63;
    int node = (w >> 2) * 64 + lane;
    int jbase = (w & 3) * 32;
    if (node >= N_NODES) return;

    float4 a[32];
    const float4* a1 = (const float4*)(A1 + (size_t)node * HID);
    if (A2) {
        const float4* a2 = (const float4*)(A2 + (size_t)node * HID);
        #pragma unroll
        for (int k = 0; k < 32; k++) {
            float4 u = a1[k], v = a2[k];
            a[k] = make_float4(u.x + v.x, u.y + v.y, u.z + v.z, u.w + v.w);
        }
    } else {
        #pragma unroll
        for (int k = 0; k < 32; k++) a[k] = a1[k];
    }

    float* o = out + (size_t)node * HID;
    for (int j0 = 0; j0 < 32; j0 += 4) {
        int j = jbase + j0;
        const float* w0 = W + (size_t)j * HID;
        const float* w1 = w0 + HID;
        const float* w2 = w1 + HID;
        const float* w3 = w2 + HID;
        float acc0 = Bv[j + 0];
        float acc1 = Bv[j + 1];
        float acc2 = Bv[j + 2];
        float acc3 = Bv[j + 3];
        #pragma unroll
        for (int k = 0; k < 32; k++) {
            float4 av = a[k];
            acc0 += av.x * w0[4*k+0]; acc0 += av.y * w0[4*k+1];
            acc0 += av.z * w0[4*k+2]; acc0 += av.w * w0[4*k+3];
            acc1 += av.x * w1[4*k+0]; acc1 += av.y * w1[4*k+1];
            acc1 += av.z * w1[4*k+2]; acc1 += av.w * w1[4*k+3];
            acc2 += av.x * w2[4*k+0]; acc2 += av.y * w2[4*k+1];
            acc2 += av.z * w2[4*k+2]; acc2 += av.w * w2[4*k+3];
            acc3 += av.x * w3[4*k+0]; acc3 += av.y * w3[4*k+1];
            acc3 += av.z * w3[4*k+2]; acc3 += av.w * w3[4*k+3];
        }
        if (apply_sp) {
            acc0 = softplus_f(acc0); acc1 = softplus_f(acc1);
            acc2 = softplus_f(acc2); acc3 = softplus_f(acc3);
        }
        float4 res = make_float4(acc0, acc1, acc2, acc3);
        *(float4*)(o + j) = res;
    }
}

// One wave per node; atomic add into graph feature.
__global__ void pool_kernel(const float* __restrict__ nf,
                            const int* __restrict__ batch,
                            float* __restrict__ gout) {
    int wave = blockIdx.x * 4 + (threadIdx.x >> 6);
    int lane = threadIdx.x & 63;
    if (wave >= N_NODES) return;
    int n = __builtin_amdgcn_readfirstlane(wave);
    int g = batch[n];
    const float2* r = (const float2*)(nf + (size_t)n * HID);
    float2 v = r[lane];
    float* gp = gout + (size_t)g * HID + lane * 2;
    unsafeAtomicAdd(gp, v.x);
    unsafeAtomicAdd(gp + 1, v.y);
}

extern "C" void kernel_launch(void* const* d_in, const int* in_sizes, int n_in,
                              void* d_out, int out_size, void* d_ws, size_t ws_size,
                              hipStream_t stream) {
    const float* node_attr = (const float*)d_in[0];
    const float* edge_attr = (const float*)d_in[1];
    const int*   ei        = (const int*)d_in[2];
    const int*   batch     = (const int*)d_in[3];
    const float* W1        = (const float*)d_in[4];
    const float* B1        = (const float*)d_in[5];
    const float* W2        = (const float*)d_in[6];
    const float* B2        = (const float*)d_in[7];

    float* gout    = (float*)d_out;                    // [64,128]
    float* nodeout = (float*)d_out + N_GRAPHS * HID;   // [50000,128]

    const size_t NH = (size_t)N_NODES * HID;
    float* agg  = (float*)d_ws;
    float* hbuf = agg + NH;
    float* xbuf = hbuf + NH;

    const int edge_blocks = (N_EDGES + 3) / 4;
    const int mlp_blocks  = ((N_NODES + 63) / 64 * 4 + 3) / 4;  // 4 waves/node-group, 4 waves/block
    const int pool_blocks = (N_NODES + 3) / 4;

    const float* xcur = node_attr;
    for (int i = 0; i < 3; i++) {
        hipMemsetAsync(agg, 0, NH * sizeof(float), stream);
        edge_agg_kernel<<<edge_blocks, 256, 0, stream>>>(xcur, edge_attr, ei, agg);
        mlp_kernel<<<mlp_blocks, 256, 0, stream>>>(agg, xcur,
                W1 + (size_t)i * HID * HID, B1 + (size_t)i * HID, hbuf, 1);
        float* xnext = (i == 2) ? nodeout : xbuf;
        mlp_kernel<<<mlp_blocks, 256, 0, stream>>>(hbuf, nullptr,
                W2 + (size_t)i * HID * HID, B2 + (size_t)i * HID, xnext, (i < 2) ? 1 : 0);
        xcur = xnext;
    }
    hipMemsetAsync(gout, 0, (size_t)N_GRAPHS * HID * sizeof(float), stream);
    pool_kernel<<<pool_blocks, 256, 0, stream>>>(nodeout, batch, gout);
}

// Round 2
// 1282.026 us; speedup vs baseline: 2.5158x; 2.5158x over previous
//
#include <hip/hip_runtime.h>
#include <math.h>

#define N_NODES 50000
#define N_EDGES 600000
#define HID 128
#define N_GRAPHS 64
#define BCAP 32        // bucket capacity; dst degree ~ Poisson(12), overflow handled
#define OVF_CAP 4096
#define PCHUNK 8

typedef __attribute__((ext_vector_type(8))) short short8;
typedef __attribute__((ext_vector_type(4))) float floatx4;

__device__ __forceinline__ float softplus_f(float v) {
    // jax.nn.softplus = max(v,0) + log1p(exp(-|v|))
    return fmaxf(v, 0.0f) + log1pf(expf(-fabsf(v)));
}

__device__ __forceinline__ unsigned short f2bf(float f) {
    unsigned u = __float_as_uint(f);
    u = (u + 0x7FFFu + ((u >> 16) & 1u)) >> 16;   // RNE; inputs finite
    return (unsigned short)u;
}

// ---- bucket build: slot = atomicAdd(cnt[dst]); store (edge, src) pairs ----
__global__ void build_buckets(const int* __restrict__ ei, int* __restrict__ cnt,
                              int2* __restrict__ bkt, int* __restrict__ ovf) {
    int e = blockIdx.x * 256 + threadIdx.x;
    if (e >= N_EDGES) return;
    int src = ei[e];
    int dst = ei[N_EDGES + e];
    int slot = atomicAdd(&cnt[dst], 1);
    if (slot < BCAP) {
        bkt[(size_t)dst * BCAP + slot] = make_int2(e, src);
    } else {
        int k = atomicAdd(&cnt[N_NODES], 1);
        if (k < OVF_CAP) ovf[k] = e;
    }
}

// ---- aggregation: wave per node, lane = feature pair; out = x[n] + sum msgs ----
__global__ void __launch_bounds__(256) agg_kernel(const float* __restrict__ x,
        const float* __restrict__ edge_attr, const int* __restrict__ cnt,
        const int2* __restrict__ bkt, float* __restrict__ out) {
    int wave = blockIdx.x * 4 + (threadIdx.x >> 6);
    int lane = threadIdx.x & 63;
    int n = __builtin_amdgcn_readfirstlane(wave);
    if (n >= N_NODES) return;
    const float2* xr = (const float2*)(x + (size_t)n * HID);
    float2 acc = xr[lane];                     // (1+eps)*x with eps=0
    int c = cnt[n]; if (c > BCAP) c = BCAP;
    const int2* bk = bkt + (size_t)n * BCAP;
    for (int s = 0; s < c; s++) {
        int2 p = bk[s];                        // wave-uniform -> scalar load
        const float2* er = (const float2*)(edge_attr + (size_t)p.x * HID);
        const float2* sr = (const float2*)(x + (size_t)p.y * HID);
        float2 ev = er[lane];
        float2 sv = sr[lane];
        acc.x += softplus_f(ev.x + sv.x);
        acc.y += softplus_f(ev.y + sv.y);
    }
    ((float2*)(out + (size_t)n * HID))[lane] = acc;
}

// ---- overflow fixup (runs after agg_kernel; expected ~0 entries) ----
__global__ void ovf_kernel(const float* __restrict__ x,
                           const float* __restrict__ edge_attr,
                           const int* __restrict__ ei,
                           const int* __restrict__ cnt,
                           const int* __restrict__ ovf,
                           float* __restrict__ out) {
    int lane = threadIdx.x & 63;
    int wid = threadIdx.x >> 6;
    int total = cnt[N_NODES]; if (total > OVF_CAP) total = OVF_CAP;
    for (int i = wid; i < total; i += 4) {
        int e = ovf[i];
        int src = ei[e];
        int dst = ei[N_EDGES + e];
        const float2* er = (const float2*)(edge_attr + (size_t)e * HID);
        const float2* sr = (const float2*)(x + (size_t)src * HID);
        float2 ev = er[lane];
        float2 sv = sr[lane];
        float* ap = out + (size_t)dst * HID + lane * 2;
        unsafeAtomicAdd(ap,     softplus_f(ev.x + sv.x));
        unsafeAtomicAdd(ap + 1, softplus_f(ev.y + sv.y));
    }
}

// ---- pack W[n][k] (f32) into MFMA B-frag layout (bf16) ----
// packed[(mat*32 + kt*8 + nt)*64 + lane][j] = bf16(W_mat[nt*16+(lane&15)][kt*32+(lane>>4)*8+j])
__global__ void pack_w(const float* __restrict__ W1, const float* __restrict__ W2,
                       unsigned short* __restrict__ pw) {
    int t = blockIdx.x * 256 + threadIdx.x;
    if (t >= 6 * 32 * 64) return;
    int lane = t & 63;
    int tile = (t >> 6) & 31;
    int mat = t >> 11;                       // 0..5 = layer*2 + which
    int kt = tile >> 3, nt = tile & 7;
    const float* W = (mat & 1) ? W2 : W1;
    W += (size_t)(mat >> 1) * HID * HID;
    int n = nt * 16 + (lane & 15);
    int kbase = kt * 32 + (lane >> 4) * 8;
    short8 v;
    #pragma unroll
    for (int j = 0; j < 8; j++) v[j] = (short)f2bf(W[(size_t)n * HID + kbase + j]);
    *((short8*)(pw + (size_t)t * 8)) = v;
}

// ---- MLP: out[r][:] = act(A[r][:] @ W^T + b), bf16 MFMA 16x16x32 ----
// wave handles 16 rows x 128 cols; A converted f32->bf16 in-register.
__global__ void __launch_bounds__(256) mlp_mfma(const float* __restrict__ A,
        const unsigned short* __restrict__ pw, const float* __restrict__ bias,
        float* __restrict__ out, int act) {
    int wave = threadIdx.x >> 6, lane = threadIdx.x & 63;
    int r0 = (blockIdx.x * 4 + wave) * 16;
    int m = lane & 15, q = lane >> 4;
    int row = r0 + m;
    bool rv = row < N_NODES;
    floatx4 zero = {0.f, 0.f, 0.f, 0.f};
    floatx4 acc[8];
    #pragma unroll
    for (int nt = 0; nt < 8; nt++) acc[nt] = zero;
    const float* arow = A + (size_t)row * HID + q * 8;
    const short8* wbase = (const short8*)pw;
    #pragma unroll
    for (int kt = 0; kt < 4; kt++) {
        short8 af = {0, 0, 0, 0, 0, 0, 0, 0};
        if (rv) {
            float4 f0 = *(const float4*)(arow + kt * 32);
            float4 f1 = *(const float4*)(arow + kt * 32 + 4);
            af[0] = (short)f2bf(f0.x); af[1] = (short)f2bf(f0.y);
            af[2] = (short)f2bf(f0.z); af[3] = (short)f2bf(f0.w);
            af[4] = (short)f2bf(f1.x); af[5] = (short)f2bf(f1.y);
            af[6] = (short)f2bf(f1.z); af[7] = (short)f2bf(f1.w);
        }
        const short8* wp = wbase + (size_t)(kt * 8) * 64 + lane;
        #pragma unroll
        for (int nt = 0; nt < 8; nt++) {
            short8 bf = wp[nt * 64];
            acc[nt] = __builtin_amdgcn_mfma_f32_16x16x32_bf16(af, bf, acc[nt], 0, 0, 0);
        }
    }
    // C/D layout: col = lane&15, row = q*4 + reg  [m89-verified]
    #pragma unroll
    for (int nt = 0; nt < 8; nt++) {
        float b = bias[nt * 16 + m];
        #pragma unroll
        for (int i = 0; i < 4; i++) {
            int r = r0 + q * 4 + i;
            if (r < N_NODES) {
                float v = acc[nt][i] + b;
                if (act) v = softplus_f(v);
                out[(size_t)r * HID + nt * 16 + m] = v;
            }
        }
    }
}

// ---- pool: batch is sorted -> segment boundaries, then chunked partial sums ----
__global__ void find_bounds(const int* __restrict__ batch, int* __restrict__ start) {
    int n = blockIdx.x * 256 + threadIdx.x;
    if (n >= N_NODES) return;
    int bn = batch[n];
    int bp = (n == 0) ? -1 : batch[n - 1];
    for (int g = bp + 1; g <= bn; g++) start[g] = n;
    if (n == N_NODES - 1)
        for (int g = bn + 1; g <= N_GRAPHS; g++) start[g] = N_NODES;
}

__global__ void pool_partial(const float* __restrict__ nf, const int* __restrict__ start,
                             float* __restrict__ part) {
    int g = blockIdx.x >> 3, c = blockIdx.x & (PCHUNK - 1);
    int j = threadIdx.x;                      // 128 threads = feature
    int s = start[g], e = start[g + 1];
    int len = e - s;
    int b0 = s + (len * c) / PCHUNK;
    int b1 = s + (len * (c + 1)) / PCHUNK;
    float acc = 0.f;
    for (int n = b0; n < b1; n++) acc += nf[(size_t)n * HID + j];
    part[(size_t)blockIdx.x * HID + j] = acc;
}

__global__ void pool_final(const float* __restrict__ part, float* __restrict__ gout) {
    int g = blockIdx.x, j = threadIdx.x;
    float acc = 0.f;
    #pragma unroll
    for (int c = 0; c < PCHUNK; c++) acc += part[(size_t)(g * PCHUNK + c) * HID + j];
    gout[(size_t)g * HID + j] = acc;
}

extern "C" void kernel_launch(void* const* d_in, const int* in_sizes, int n_in,
                              void* d_out, int out_size, void* d_ws, size_t ws_size,
                              hipStream_t stream) {
    const float* node_attr = (const float*)d_in[0];
    const float* edge_attr = (const float*)d_in[1];
    const int*   ei        = (const int*)d_in[2];
    const int*   batch     = (const int*)d_in[3];
    const float* W1        = (const float*)d_in[4];
    const float* B1        = (const float*)d_in[5];
    const float* W2        = (const float*)d_in[6];
    const float* B2        = (const float*)d_in[7];

    float* gout    = (float*)d_out;                    // [64,128]
    float* nodeout = (float*)d_out + N_GRAPHS * HID;   // [50000,128]

    const size_t NH = (size_t)N_NODES * HID;
    // workspace layout (~64.7 MB)
    float* P   = (float*)d_ws;                         // NH
    float* Q   = P + NH;                               // NH
    int*   cnt = (int*)(Q + NH);                       // 50002 (cnt[50000]=ovf counter)
    int*   ovf = cnt + 50002;                          // OVF_CAP
    int2*  bkt = (int2*)(ovf + OVF_CAP);               // 50000*BCAP
    unsigned short* pw = (unsigned short*)(bkt + (size_t)N_NODES * BCAP);  // 6*16384
    int*   startb = (int*)(pw + 6 * 16384);            // 65
    float* part = (float*)(startb + 66);               // 64*PCHUNK*128

    hipMemsetAsync(cnt, 0, (size_t)50001 * sizeof(int), stream);
    build_buckets<<<(N_EDGES + 255) / 256, 256, 0, stream>>>(ei, cnt, bkt, ovf);
    pack_w<<<(6 * 32 * 64 + 255) / 256, 256, 0, stream>>>(W1, W2, pw);
    find_bounds<<<(N_NODES + 255) / 256, 256, 0, stream>>>(batch, startb);

    const int agg_blocks = (N_NODES + 3) / 4;
    const int mlp_blocks = (N_NODES + 63) / 64;

    const float* xcur = node_attr;
    float* bufA = P;   // agg/h ping-pong
    float* bufB = Q;
    for (int i = 0; i < 3; i++) {
        // bufA <- agg(xcur); bufB <- mlp1(bufA); (xnext = bufA or nodeout) <- mlp2(bufB)
        agg_kernel<<<agg_blocks, 256, 0, stream>>>(xcur, edge_attr, cnt, bkt, bufA);
        ovf_kernel<<<1, 256, 0, stream>>>(xcur, edge_attr, ei, cnt, ovf, bufA);
        mlp_mfma<<<mlp_blocks, 256, 0, stream>>>(bufA, pw + (size_t)(i * 2) * 16384,
                B1 + (size_t)i * HID, bufB, 1);
        float* xnext = (i == 2) ? nodeout : bufA;
        mlp_mfma<<<mlp_blocks, 256, 0, stream>>>(bufB, pw + (size_t)(i * 2 + 1) * 16384,
                B2 + (size_t)i * HID, xnext, (i < 2) ? 1 : 0);
        xcur = xnext;
        // swap roles: next layer's agg writes into the now-dead bufB
        float* t = bufA; bufA = bufB; bufB = t;
    }
    pool_partial<<<N_GRAPHS * PCHUNK, HID, 0, stream>>>(nodeout, startb, part);
    pool_final<<<N_GRAPHS, HID, 0, stream>>>(part, gout);
}

// Round 3
// 839.627 us; speedup vs baseline: 3.8414x; 1.5269x over previous
//
#include <hip/hip_runtime.h>
#include <math.h>

#define N_NODES 50000
#define N_EDGES 600000
#define HID 128
#define N_GRAPHS 64
#define BCAP 32        // bucket capacity; dst degree ~ Poisson(12), overflow handled
#define OVF_CAP 4096
#define PCHUNK 8

typedef __attribute__((ext_vector_type(8))) short short8;
typedef __attribute__((ext_vector_type(4))) float floatx4;

// fast softplus: max(v,0) + ln(1 + e^-|v|) via v_exp_f32/v_log_f32 (~1e-6 rel)
__device__ __forceinline__ float softplus_f(float v) {
    return fmaxf(v, 0.0f) + __logf(1.0f + __expf(-fabsf(v)));
}

__device__ __forceinline__ float4 sp4(float4 a, float4 b) {
    return make_float4(softplus_f(a.x + b.x), softplus_f(a.y + b.y),
                       softplus_f(a.z + b.z), softplus_f(a.w + b.w));
}

__device__ __forceinline__ unsigned short f2bf(float f) {
    unsigned u = __float_as_uint(f);
    u = (u + 0x7FFFu + ((u >> 16) & 1u)) >> 16;   // RNE; inputs finite
    return (unsigned short)u;
}

// ---- bucket build: slot = atomicAdd(cnt[dst]); store (edge, src) pairs ----
__global__ void build_buckets(const int* __restrict__ ei, int* __restrict__ cnt,
                              int2* __restrict__ bkt, int* __restrict__ ovf) {
    int e = blockIdx.x * 256 + threadIdx.x;
    if (e >= N_EDGES) return;
    int src = ei[e];
    int dst = ei[N_EDGES + e];
    int slot = atomicAdd(&cnt[dst], 1);
    if (slot < BCAP) {
        bkt[(size_t)dst * BCAP + slot] = make_int2(e, src);
    } else {
        int k = atomicAdd(&cnt[N_NODES], 1);
        if (k < OVF_CAP) ovf[k] = e;
    }
}

// ---- aggregation: wave per node; half-wave per edge, float4 per lane ----
// out[n] = x[n] + sum_e softplus(x[src_e] + edge_attr[e])
__global__ void __launch_bounds__(256) agg_kernel(const float* __restrict__ x,
        const float* __restrict__ edge_attr, const int* __restrict__ cnt,
        const int2* __restrict__ bkt, float* __restrict__ out) {
    int wave = blockIdx.x * 4 + (threadIdx.x >> 6);
    int lane = threadIdx.x & 63;
    int n = __builtin_amdgcn_readfirstlane(wave);
    if (n >= N_NODES) return;
    int h = lane >> 5;          // which edge of the pair this half-wave handles
    int l = lane & 31;          // float4 index within the 128-feat row
    int c = cnt[n]; if (c > BCAP) c = BCAP;
    const int2* bk = bkt + (size_t)n * BCAP;
    float4 acc = make_float4(0.f, 0.f, 0.f, 0.f);
    int s = 0;
    // 4 edges per iteration: 2 per half-wave, 8 independent float4 loads in flight
    for (; s + 4 <= c; s += 4) {
        int2 pA = bk[s + h];
        int2 pB = bk[s + 2 + h];
        float4 eA = *(const float4*)(edge_attr + (size_t)pA.x * HID + l * 4);
        float4 xA = *(const float4*)(x + (size_t)pA.y * HID + l * 4);
        float4 eB = *(const float4*)(edge_attr + (size_t)pB.x * HID + l * 4);
        float4 xB = *(const float4*)(x + (size_t)pB.y * HID + l * 4);
        float4 mA = sp4(eA, xA);
        float4 mB = sp4(eB, xB);
        acc.x += mA.x + mB.x; acc.y += mA.y + mB.y;
        acc.z += mA.z + mB.z; acc.w += mA.w + mB.w;
    }
    if (s + 2 <= c) {
        int2 p = bk[s + h];
        float4 ev = *(const float4*)(edge_attr + (size_t)p.x * HID + l * 4);
        float4 xv = *(const float4*)(x + (size_t)p.y * HID + l * 4);
        float4 m = sp4(ev, xv);
        acc.x += m.x; acc.y += m.y; acc.z += m.z; acc.w += m.w;
        s += 2;
    }
    if (s < c && h == 0) {      // odd tail: half-wave 0 only
        int2 p = bk[s];
        float4 ev = *(const float4*)(edge_attr + (size_t)p.x * HID + l * 4);
        float4 xv = *(const float4*)(x + (size_t)p.y * HID + l * 4);
        float4 m = sp4(ev, xv);
        acc.x += m.x; acc.y += m.y; acc.z += m.z; acc.w += m.w;
    }
    // combine the two half-waves: lane l (<32) += lane l+32
    acc.x += __shfl(acc.x, l + 32);
    acc.y += __shfl(acc.y, l + 32);
    acc.z += __shfl(acc.z, l + 32);
    acc.w += __shfl(acc.w, l + 32);
    if (h == 0) {
        float4 xn = *(const float4*)(x + (size_t)n * HID + l * 4);
        acc.x += xn.x; acc.y += xn.y; acc.z += xn.z; acc.w += xn.w;
        *(float4*)(out + (size_t)n * HID + l * 4) = acc;
    }
}

// ---- overflow fixup (runs after agg_kernel; expected ~0 entries) ----
__global__ void ovf_kernel(const float* __restrict__ x,
                           const float* __restrict__ edge_attr,
                           const int* __restrict__ ei,
                           const int* __restrict__ cnt,
                           const int* __restrict__ ovf,
                           float* __restrict__ out) {
    int lane = threadIdx.x & 63;
    int wid = threadIdx.x >> 6;
    int total = cnt[N_NODES]; if (total > OVF_CAP) total = OVF_CAP;
    for (int i = wid; i < total; i += 4) {
        int e = ovf[i];
        int src = ei[e];
        int dst = ei[N_EDGES + e];
        const float2* er = (const float2*)(edge_attr + (size_t)e * HID);
        const float2* sr = (const float2*)(x + (size_t)src * HID);
        float2 ev = er[lane];
        float2 sv = sr[lane];
        float* ap = out + (size_t)dst * HID + lane * 2;
        unsafeAtomicAdd(ap,     softplus_f(ev.x + sv.x));
        unsafeAtomicAdd(ap + 1, softplus_f(ev.y + sv.y));
    }
}

// ---- pack W[n][k] (f32) into MFMA B-frag layout (bf16) ----
// packed[(mat*32 + kt*8 + nt)*64 + lane][j] = bf16(W_mat[nt*16+(lane&15)][kt*32+(lane>>4)*8+j])
__global__ void pack_w(const float* __restrict__ W1, const float* __restrict__ W2,
                       unsigned short* __restrict__ pw) {
    int t = blockIdx.x * 256 + threadIdx.x;
    if (t >= 6 * 32 * 64) return;
    int lane = t & 63;
    int tile = (t >> 6) & 31;
    int mat = t >> 11;                       // 0..5 = layer*2 + which
    int kt = tile >> 3, nt = tile & 7;
    const float* W = (mat & 1) ? W2 : W1;
    W += (size_t)(mat >> 1) * HID * HID;
    int n = nt * 16 + (lane & 15);
    int kbase = kt * 32 + (lane >> 4) * 8;
    short8 v;
    #pragma unroll
    for (int j = 0; j < 8; j++) v[j] = (short)f2bf(W[(size_t)n * HID + kbase + j]);
    *((short8*)(pw + (size_t)t * 8)) = v;
}

// ---- MLP: out[r][:] = act(A[r][:] @ W^T + b), bf16 MFMA 16x16x32 ----
// block = 4 waves: 2 row-tiles x 2 col-halves; wave = 16 rows x 64 cols.
__global__ void __launch_bounds__(256) mlp_mfma(const float* __restrict__ A,
        const unsigned short* __restrict__ pw, const float* __restrict__ bias,
        float* __restrict__ out, int act) {
    int wave = threadIdx.x >> 6, lane = threadIdx.x & 63;
    int r0 = (blockIdx.x * 2 + (wave >> 1)) * 16;
    int ch = wave & 1;                        // column half: cols [ch*64, ch*64+64)
    int m = lane & 15, q = lane >> 4;
    int row = r0 + m;
    bool rv = row < N_NODES;
    floatx4 zero = {0.f, 0.f, 0.f, 0.f};
    floatx4 acc[4];
    #pragma unroll
    for (int t = 0; t < 4; t++) acc[t] = zero;
    const float* arow = A + (size_t)row * HID + q * 8;
    const short8* wbase = (const short8*)pw;
    #pragma unroll
    for (int kt = 0; kt < 4; kt++) {
        short8 af = {0, 0, 0, 0, 0, 0, 0, 0};
        if (rv) {
            float4 f0 = *(const float4*)(arow + kt * 32);
            float4 f1 = *(const float4*)(arow + kt * 32 + 4);
            af[0] = (short)f2bf(f0.x); af[1] = (short)f2bf(f0.y);
            af[2] = (short)f2bf(f0.z); af[3] = (short)f2bf(f0.w);
            af[4] = (short)f2bf(f1.x); af[5] = (short)f2bf(f1.y);
            af[6] = (short)f2bf(f1.z); af[7] = (short)f2bf(f1.w);
        }
        const short8* wp = wbase + (size_t)(kt * 8 + ch * 4) * 64 + lane;
        #pragma unroll
        for (int t = 0; t < 4; t++) {
            short8 bf = wp[t * 64];
            acc[t] = __builtin_amdgcn_mfma_f32_16x16x32_bf16(af, bf, acc[t], 0, 0, 0);
        }
    }
    // C/D layout: col = lane&15, row = q*4 + reg  [m89-verified]
    #pragma unroll
    for (int t = 0; t < 4; t++) {
        int col = (ch * 4 + t) * 16 + m;
        float b = bias[col];
        #pragma unroll
        for (int i = 0; i < 4; i++) {
            int r = r0 + q * 4 + i;
            if (r < N_NODES) {
                float v = acc[t][i] + b;
                if (act) v = softplus_f(v);
                out[(size_t)r * HID + col] = v;
            }
        }
    }
}

// ---- pool: batch is sorted -> segment boundaries, then chunked partial sums ----
__global__ void find_bounds(const int* __restrict__ batch, int* __restrict__ start) {
    int n = blockIdx.x * 256 + threadIdx.x;
    if (n >= N_NODES) return;
    int bn = batch[n];
    int bp = (n == 0) ? -1 : batch[n - 1];
    for (int g = bp + 1; g <= bn; g++) start[g] = n;
    if (n == N_NODES - 1)
        for (int g = bn + 1; g <= N_GRAPHS; g++) start[g] = N_NODES;
}

__global__ void pool_partial(const float* __restrict__ nf, const int* __restrict__ start,
                             float* __restrict__ part) {
    int g = blockIdx.x >> 3, c = blockIdx.x & (PCHUNK - 1);
    int j = threadIdx.x;                      // 128 threads = feature
    int s = start[g], e = start[g + 1];
    int len = e - s;
    int b0 = s + (len * c) / PCHUNK;
    int b1 = s + (len * (c + 1)) / PCHUNK;
    float acc = 0.f;
    for (int n = b0; n < b1; n++) acc += nf[(size_t)n * HID + j];
    part[(size_t)blockIdx.x * HID + j] = acc;
}

__global__ void pool_final(const float* __restrict__ part, float* __restrict__ gout) {
    int g = blockIdx.x, j = threadIdx.x;
    float acc = 0.f;
    #pragma unroll
    for (int c = 0; c < PCHUNK; c++) acc += part[(size_t)(g * PCHUNK + c) * HID + j];
    gout[(size_t)g * HID + j] = acc;
}

extern "C" void kernel_launch(void* const* d_in, const int* in_sizes, int n_in,
                              void* d_out, int out_size, void* d_ws, size_t ws_size,
                              hipStream_t stream) {
    const float* node_attr = (const float*)d_in[0];
    const float* edge_attr = (const float*)d_in[1];
    const int*   ei        = (const int*)d_in[2];
    const int*   batch     = (const int*)d_in[3];
    const float* W1        = (const float*)d_in[4];
    const float* B1        = (const float*)d_in[5];
    const float* W2        = (const float*)d_in[6];
    const float* B2        = (const float*)d_in[7];

    float* gout    = (float*)d_out;                    // [64,128]
    float* nodeout = (float*)d_out + N_GRAPHS * HID;   // [50000,128]

    const size_t NH = (size_t)N_NODES * HID;
    float* P   = (float*)d_ws;                         // NH
    float* Q   = P + NH;                               // NH
    int*   cnt = (int*)(Q + NH);                       // 50002 (cnt[50000]=ovf counter)
    int*   ovf = cnt + 50002;                          // OVF_CAP
    int2*  bkt = (int2*)(ovf + OVF_CAP);               // 50000*BCAP
    unsigned short* pw = (unsigned short*)(bkt + (size_t)N_NODES * BCAP);  // 6*16384
    int*   startb = (int*)(pw + 6 * 16384);            // 65
    float* part = (float*)(startb + 66);               // 64*PCHUNK*128

    hipMemsetAsync(cnt, 0, (size_t)50001 * sizeof(int), stream);
    build_buckets<<<(N_EDGES + 255) / 256, 256, 0, stream>>>(ei, cnt, bkt, ovf);
    pack_w<<<(6 * 32 * 64 + 255) / 256, 256, 0, stream>>>(W1, W2, pw);
    find_bounds<<<(N_NODES + 255) / 256, 256, 0, stream>>>(batch, startb);

    const int agg_blocks = (N_NODES + 3) / 4;
    const int mlp_blocks = (N_NODES + 31) / 32;        // 2 row-tiles / block

    const float* xcur = node_attr;
    float* bufA = P;
    float* bufB = Q;
    for (int i = 0; i < 3; i++) {
        agg_kernel<<<agg_blocks, 256, 0, stream>>>(xcur, edge_attr, cnt, bkt, bufA);
        ovf_kernel<<<1, 256, 0, stream>>>(xcur, edge_attr, ei, cnt, ovf, bufA);
        mlp_mfma<<<mlp_blocks, 256, 0, stream>>>(bufA, pw + (size_t)(i * 2) * 16384,
                B1 + (size_t)i * HID, bufB, 1);
        float* xnext = (i == 2) ? nodeout : bufA;
        mlp_mfma<<<mlp_blocks, 256, 0, stream>>>(bufB, pw + (size_t)(i * 2 + 1) * 16384,
                B2 + (size_t)i * HID, xnext, (i < 2) ? 1 : 0);
        xcur = xnext;
        float* t = bufA; bufA = bufB; bufB = t;
    }
    pool_partial<<<N_GRAPHS * PCHUNK, HID, 0, stream>>>(nodeout, startb, part);
    pool_final<<<N_GRAPHS, HID, 0, stream>>>(part, gout);
}

// Round 4
// 745.388 us; speedup vs baseline: 4.3271x; 1.1264x over previous
//
#include <hip/hip_runtime.h>
#include <math.h>

#define N_NODES 50000
#define N_EDGES 600000
#define HID 128
#define N_GRAPHS 64
#define BCAP 32        // bucket capacity; overflow folded into agg rare path
#define OVF_CAP 4096
#define PCHUNK 8
#define LDSP 136       // padded LDS row stride (bf16): 272B = 17*16B -> bank-rotates A-frag reads

typedef __attribute__((ext_vector_type(8))) short short8;
typedef __attribute__((ext_vector_type(4))) float floatx4;

__device__ __forceinline__ float softplus_f(float v) {
    return fmaxf(v, 0.0f) + __logf(1.0f + __expf(-fabsf(v)));
}
__device__ __forceinline__ unsigned short f2bf(float f) {
    unsigned u = __float_as_uint(f);
    u = (u + 0x7FFFu + ((u >> 16) & 1u)) >> 16;   // RNE; inputs finite
    return (unsigned short)u;
}
__device__ __forceinline__ float bflo(unsigned u) { return __uint_as_float(u << 16); }
__device__ __forceinline__ float bfhi(unsigned u) { return __uint_as_float(u & 0xFFFF0000u); }

// ---- f32 -> bf16 row-major pack (node_attr) ----
__global__ void pack_x(const float* __restrict__ xf, unsigned short* __restrict__ xb, int nelem4) {
    int t = blockIdx.x * 256 + threadIdx.x;
    if (t >= nelem4) return;
    float4 v = *(const float4*)(xf + (size_t)t * 4);
    unsigned o0 = (unsigned)f2bf(v.x) | ((unsigned)f2bf(v.y) << 16);
    unsigned o1 = (unsigned)f2bf(v.z) | ((unsigned)f2bf(v.w) << 16);
    *(uint2*)(xb + (size_t)t * 4) = make_uint2(o0, o1);
}

// ---- bucket build: slot = atomicAdd(cnt[dst]); overflow keeps (e,src,dst) ----
__global__ void build_buckets(const int* __restrict__ ei, int* __restrict__ cnt,
                              int2* __restrict__ bkt, int4* __restrict__ ovf) {
    int e = blockIdx.x * 256 + threadIdx.x;
    if (e >= N_EDGES) return;
    int src = ei[e];
    int dst = ei[N_EDGES + e];
    int slot = atomicAdd(&cnt[dst], 1);
    if (slot < BCAP) {
        bkt[(size_t)dst * BCAP + slot] = make_int2(e, src);
    } else {
        int k = atomicAdd(&cnt[N_NODES], 1);
        if (k < OVF_CAP) ovf[k] = make_int4(e, src, dst, 0);
    }
}

// ---- aggregation: wave/node, half-wave/edge, float4 feats; x in bf16 ----
// outb[n] = bf16( x[n] + sum_e softplus(edge_attr[e] + x[src_e]) )
__global__ void __launch_bounds__(256) agg_kernel(const unsigned short* __restrict__ xb,
        const float* __restrict__ edge_attr, const int* __restrict__ cnt,
        const int2* __restrict__ bkt, const int4* __restrict__ ovf,
        unsigned short* __restrict__ outb) {
    int wave = blockIdx.x * 4 + (threadIdx.x >> 6);
    int lane = threadIdx.x & 63;
    int n = __builtin_amdgcn_readfirstlane(wave);
    if (n >= N_NODES) return;
    int h = lane >> 5;          // which edge of a pair this half-wave handles
    int l = lane & 31;          // float4 index in the 128-feat row
    int ctot = cnt[n];
    int c = ctot < BCAP ? ctot : BCAP;
    const int2* bk = bkt + (size_t)n * BCAP;
    float4 acc = make_float4(0.f, 0.f, 0.f, 0.f);
    int s = 0;
    for (; s + 4 <= c; s += 4) {
        int2 pA = bk[s + h];
        int2 pB = bk[s + 2 + h];
        float4 eA = *(const float4*)(edge_attr + (size_t)pA.x * HID + l * 4);
        uint2  xA = *(const uint2*)(xb + (size_t)pA.y * HID + l * 4);
        float4 eB = *(const float4*)(edge_attr + (size_t)pB.x * HID + l * 4);
        uint2  xB = *(const uint2*)(xb + (size_t)pB.y * HID + l * 4);
        acc.x += softplus_f(eA.x + bflo(xA.x)) + softplus_f(eB.x + bflo(xB.x));
        acc.y += softplus_f(eA.y + bfhi(xA.x)) + softplus_f(eB.y + bfhi(xB.x));
        acc.z += softplus_f(eA.z + bflo(xA.y)) + softplus_f(eB.z + bflo(xB.y));
        acc.w += softplus_f(eA.w + bfhi(xA.y)) + softplus_f(eB.w + bfhi(xB.y));
    }
    if (s + 2 <= c) {
        int2 p = bk[s + h];
        float4 ev = *(const float4*)(edge_attr + (size_t)p.x * HID + l * 4);
        uint2  xv = *(const uint2*)(xb + (size_t)p.y * HID + l * 4);
        acc.x += softplus_f(ev.x + bflo(xv.x));
        acc.y += softplus_f(ev.y + bfhi(xv.x));
        acc.z += softplus_f(ev.z + bflo(xv.y));
        acc.w += softplus_f(ev.w + bfhi(xv.y));
        s += 2;
    }
    if (s < c && h == 0) {
        int2 p = bk[s];
        float4 ev = *(const float4*)(edge_attr + (size_t)p.x * HID + l * 4);
        uint2  xv = *(const uint2*)(xb + (size_t)p.y * HID + l * 4);
        acc.x += softplus_f(ev.x + bflo(xv.x));
        acc.y += softplus_f(ev.y + bfhi(xv.x));
        acc.z += softplus_f(ev.z + bflo(xv.y));
        acc.w += softplus_f(ev.w + bfhi(xv.y));
    }
    if (ctot > BCAP) {          // rare: scan overflow list for this dst
        int k = cnt[N_NODES]; if (k > OVF_CAP) k = OVF_CAP;
        for (int i = 0; i < k; i++) {
            int4 t = ovf[i];
            if (t.z == n && h == 0) {
                float4 ev = *(const float4*)(edge_attr + (size_t)t.x * HID + l * 4);
                uint2  xv = *(const uint2*)(xb + (size_t)t.y * HID + l * 4);
                acc.x += softplus_f(ev.x + bflo(xv.x));
                acc.y += softplus_f(ev.y + bfhi(xv.x));
                acc.z += softplus_f(ev.z + bflo(xv.y));
                acc.w += softplus_f(ev.w + bfhi(xv.y));
            }
        }
    }
    acc.x += __shfl(acc.x, l + 32);
    acc.y += __shfl(acc.y, l + 32);
    acc.z += __shfl(acc.z, l + 32);
    acc.w += __shfl(acc.w, l + 32);
    if (h == 0) {
        uint2 xn = *(const uint2*)(xb + (size_t)n * HID + l * 4);
        acc.x += bflo(xn.x); acc.y += bfhi(xn.x);
        acc.z += bflo(xn.y); acc.w += bfhi(xn.y);
        unsigned o0 = (unsigned)f2bf(acc.x) | ((unsigned)f2bf(acc.y) << 16);
        unsigned o1 = (unsigned)f2bf(acc.z) | ((unsigned)f2bf(acc.w) << 16);
        *(uint2*)(outb + (size_t)n * HID + l * 4) = make_uint2(o0, o1);
    }
}

// ---- pack W[n][k] (f32) into MFMA B-frag layout (bf16) ----
__global__ void pack_w(const float* __restrict__ W1, const float* __restrict__ W2,
                       unsigned short* __restrict__ pw) {
    int t = blockIdx.x * 256 + threadIdx.x;
    if (t >= 6 * 32 * 64) return;
    int lane = t & 63;
    int tile = (t >> 6) & 31;
    int mat = t >> 11;                       // 0..5 = layer*2 + which
    int kt = tile >> 3, nt = tile & 7;
    const float* W = (mat & 1) ? W2 : W1;
    W += (size_t)(mat >> 1) * HID * HID;
    int n = nt * 16 + (lane & 15);
    int kbase = kt * 32 + (lane >> 4) * 8;
    short8 v;
    #pragma unroll
    for (int j = 0; j < 8; j++) v[j] = (short)f2bf(W[(size_t)n * HID + kbase + j]);
    *((short8*)(pw + (size_t)t * 8)) = v;
}

// ---- fused MLP: out = [softplus]( softplus(A@W1^T+b1) @ W2^T + b2 ) ----
// block = 4 waves: 2 row-tiles x 2 col-halves; h round-trips via LDS (bf16).
__global__ void __launch_bounds__(256) mlp_fused(const unsigned short* __restrict__ A,
        const unsigned short* __restrict__ pw1, const unsigned short* __restrict__ pw2,
        const float* __restrict__ b1, const float* __restrict__ b2,
        void* __restrict__ outp, int final_layer) {
    __shared__ __align__(16) unsigned short hl[2][16][LDSP];
    int wave = threadIdx.x >> 6, lane = threadIdx.x & 63;
    int rt = wave >> 1, ch = wave & 1;
    int m = lane & 15, q = lane >> 4;
    int r0 = blockIdx.x * 32 + rt * 16;
    int row = r0 + m;
    bool rv = row < N_NODES;
    short8 zf = {0, 0, 0, 0, 0, 0, 0, 0};
    floatx4 zero = {0.f, 0.f, 0.f, 0.f};
    floatx4 acc[4];
    #pragma unroll
    for (int t = 0; t < 4; t++) acc[t] = zero;
    const short8* ar = (const short8*)(A + (size_t)row * HID + q * 8);
    const short8* w1 = (const short8*)pw1;
    #pragma unroll
    for (int kt = 0; kt < 4; kt++) {
        short8 af = rv ? ar[kt * 4] : zf;   // A[row][kt*32+q*8 ..+8], direct bf16
        const short8* wp = w1 + (size_t)(kt * 8 + ch * 4) * 64 + lane;
        #pragma unroll
        for (int t = 0; t < 4; t++)
            acc[t] = __builtin_amdgcn_mfma_f32_16x16x32_bf16(af, wp[t * 64], acc[t], 0, 0, 0);
    }
    // epilogue 1: h = softplus(acc + b1) -> bf16 -> LDS (C-layout -> A-layout)
    #pragma unroll
    for (int t = 0; t < 4; t++) {
        int col = ch * 64 + t * 16 + m;
        float bb = b1[col];
        #pragma unroll
        for (int i = 0; i < 4; i++)
            hl[rt][q * 4 + i][col] = f2bf(softplus_f(acc[t][i] + bb));
    }
    __syncthreads();
    #pragma unroll
    for (int t = 0; t < 4; t++) acc[t] = zero;
    const short8* w2 = (const short8*)pw2;
    #pragma unroll
    for (int kt = 0; kt < 4; kt++) {
        short8 af = *(const short8*)&hl[rt][m][kt * 32 + q * 8];
        const short8* wp = w2 + (size_t)(kt * 8 + ch * 4) * 64 + lane;
        #pragma unroll
        for (int t = 0; t < 4; t++)
            acc[t] = __builtin_amdgcn_mfma_f32_16x16x32_bf16(af, wp[t * 64], acc[t], 0, 0, 0);
    }
    if (final_layer) {
        float* out = (float*)outp;
        #pragma unroll
        for (int t = 0; t < 4; t++) {
            int col = ch * 64 + t * 16 + m;
            float bb = b2[col];
            #pragma unroll
            for (int i = 0; i < 4; i++) {
                int r = r0 + q * 4 + i;
                if (r < N_NODES) out[(size_t)r * HID + col] = acc[t][i] + bb;
            }
        }
    } else {
        __syncthreads();    // all GEMM2 LDS reads done before overwrite
        #pragma unroll
        for (int t = 0; t < 4; t++) {
            int col = ch * 64 + t * 16 + m;
            float bb = b2[col];
            #pragma unroll
            for (int i = 0; i < 4; i++)
                hl[rt][q * 4 + i][col] = f2bf(softplus_f(acc[t][i] + bb));
        }
        __syncthreads();
        // coalesced copy-out: thread -> (row = tid>>3, 16-col segment)
        unsigned short* outb = (unsigned short*)outp;
        int tid = threadIdx.x;
        int orow = tid >> 3, cseg = (tid & 7) * 16;
        int gr = blockIdx.x * 32 + orow;
        if (gr < N_NODES) {
            uint4 v0 = *(const uint4*)&hl[orow >> 4][orow & 15][cseg];
            uint4 v1 = *(const uint4*)&hl[orow >> 4][orow & 15][cseg + 8];
            *(uint4*)(outb + (size_t)gr * HID + cseg) = v0;
            *(uint4*)(outb + (size_t)gr * HID + cseg + 8) = v1;
        }
    }
}

// ---- pool: sorted batch -> boundaries -> chunked partials -> reduce ----
__global__ void find_bounds(const int* __restrict__ batch, int* __restrict__ start) {
    int n = blockIdx.x * 256 + threadIdx.x;
    if (n >= N_NODES) return;
    int bn = batch[n];
    int bp = (n == 0) ? -1 : batch[n - 1];
    for (int g = bp + 1; g <= bn; g++) start[g] = n;
    if (n == N_NODES - 1)
        for (int g = bn + 1; g <= N_GRAPHS; g++) start[g] = N_NODES;
}

__global__ void pool_partial(const float* __restrict__ nf, const int* __restrict__ start,
                             float* __restrict__ part) {
    int g = blockIdx.x >> 3, c = blockIdx.x & (PCHUNK - 1);
    int j = threadIdx.x;
    int s = start[g], e = start[g + 1];
    int len = e - s;
    int b0 = s + (len * c) / PCHUNK;
    int b1 = s + (len * (c + 1)) / PCHUNK;
    float acc = 0.f;
    for (int n = b0; n < b1; n++) acc += nf[(size_t)n * HID + j];
    part[(size_t)blockIdx.x * HID + j] = acc;
}

__global__ void pool_final(const float* __restrict__ part, float* __restrict__ gout) {
    int g = blockIdx.x, j = threadIdx.x;
    float acc = 0.f;
    #pragma unroll
    for (int c = 0; c < PCHUNK; c++) acc += part[(size_t)(g * PCHUNK + c) * HID + j];
    gout[(size_t)g * HID + j] = acc;
}

extern "C" void kernel_launch(void* const* d_in, const int* in_sizes, int n_in,
                              void* d_out, int out_size, void* d_ws, size_t ws_size,
                              hipStream_t stream) {
    const float* node_attr = (const float*)d_in[0];
    const float* edge_attr = (const float*)d_in[1];
    const int*   ei        = (const int*)d_in[2];
    const int*   batch     = (const int*)d_in[3];
    const float* W1        = (const float*)d_in[4];
    const float* B1        = (const float*)d_in[5];
    const float* W2        = (const float*)d_in[6];
    const float* B2        = (const float*)d_in[7];

    float* gout    = (float*)d_out;                    // [64,128]
    float* nodeout = (float*)d_out + N_GRAPHS * HID;   // [50000,128]

    const size_t NH = (size_t)N_NODES * HID;
    unsigned short* nab  = (unsigned short*)d_ws;      // bf16 node_attr
    unsigned short* bufA = nab + NH;                   // bf16 agg out (MLP A)
    unsigned short* bufB = bufA + NH;                  // bf16 x between layers
    int*   cnt = (int*)(bufB + NH);                    // 50001 (+pad)
    int4*  ovf = (int4*)(cnt + 50004);                 // OVF_CAP (16B aligned)
    int2*  bkt = (int2*)(ovf + OVF_CAP);               // 50000*BCAP
    unsigned short* pw = (unsigned short*)(bkt + (size_t)N_NODES * BCAP);  // 6*16384
    int*   startb = (int*)(pw + 6 * 16384);            // 65 (+pad)
    float* part = (float*)(startb + 68);               // 64*PCHUNK*128

    hipMemsetAsync(cnt, 0, (size_t)50001 * sizeof(int), stream);
    build_buckets<<<(N_EDGES + 255) / 256, 256, 0, stream>>>(ei, cnt, bkt, ovf);
    pack_w<<<(6 * 32 * 64 + 255) / 256, 256, 0, stream>>>(W1, W2, pw);
    pack_x<<<((int)(NH / 4) + 255) / 256, 256, 0, stream>>>(node_attr, nab, (int)(NH / 4));
    find_bounds<<<(N_NODES + 255) / 256, 256, 0, stream>>>(batch, startb);

    const int agg_blocks = (N_NODES + 3) / 4;
    const int mlp_blocks = (N_NODES + 31) / 32;

    const unsigned short* xcur = nab;
    for (int i = 0; i < 3; i++) {
        agg_kernel<<<agg_blocks, 256, 0, stream>>>(xcur, edge_attr, cnt, bkt, ovf, bufA);
        void* outp = (i == 2) ? (void*)nodeout : (void*)bufB;
        mlp_fused<<<mlp_blocks, 256, 0, stream>>>(bufA,
                pw + (size_t)(i * 2) * 16384, pw + (size_t)(i * 2 + 1) * 16384,
                B1 + (size_t)i * HID, B2 + (size_t)i * HID, outp, (i == 2) ? 1 : 0);
        xcur = bufB;
    }
    pool_partial<<<N_GRAPHS * PCHUNK, HID, 0, stream>>>(nodeout, startb, part);
    pool_final<<<N_GRAPHS, HID, 0, stream>>>(part, gout);
}